// Round 22
// baseline (98.256 us; speedup 1.0000x reference)
//
#include <hip/hip_runtime.h>

#define HID 768
#define NHEAD 12
#define HD 64
#define SEQ 2048
#define BATCH 2
#define PH (BATCH * NHEAD * SEQ * HD)   // 3,145,728 elements per Q/K/V plane
#define XEL (BATCH * SEQ * HID)
#define LOG2E 1.4426950408889634f
#define C1 (0.125f * LOG2E)             // QK scale folded with log2e
#define FMAX2 16.0f                     // fixed softmax max (log2 domain)

typedef __attribute__((ext_vector_type(8))) short bf16x8;
typedef __attribute__((ext_vector_type(4))) short bf16x4;
typedef __attribute__((ext_vector_type(4))) float f32x4;
typedef __attribute__((ext_vector_type(16))) float f32x16;

static __device__ __forceinline__ short f2b(float f) {
  unsigned int u = __builtin_bit_cast(unsigned int, f);
  unsigned int r = (u + 0x7fffu + ((u >> 16) & 1u)) >> 16;
  return (short)(unsigned short)r;
}

static __device__ __forceinline__ float fexp2(float x) {
  float r; asm("v_exp_f32 %0, %1" : "=v"(r) : "v"(x)); return r;
}

// ---------------------------------------------------------------------------
// Prep (byte-identical to round 21)
// ---------------------------------------------------------------------------
__global__ __launch_bounds__(256) void prep(
    const float* __restrict__ X,
    const float* __restrict__ Wq, const float* __restrict__ Wk,
    const float* __restrict__ Wv, const float* __restrict__ mask,
    short* __restrict__ Xb, short* __restrict__ Wt, float* __restrict__ mask2)
{
  __shared__ short T[64][65];
  const int t = threadIdx.x;
  const int blk = blockIdx.x;
  if (blk < 768) {
    const size_t base = (size_t)blk * 4096 + t * 16;
    f32x4 a0 = *(const f32x4*)(X + base);
    f32x4 a1 = *(const f32x4*)(X + base + 4);
    f32x4 a2 = *(const f32x4*)(X + base + 8);
    f32x4 a3 = *(const f32x4*)(X + base + 12);
    bf16x8 o0, o1;
#pragma unroll
    for (int i = 0; i < 4; ++i) {
      o0[i] = f2b(a0[i]); o0[4 + i] = f2b(a1[i]);
      o1[i] = f2b(a2[i]); o1[4 + i] = f2b(a3[i]);
    }
    *(bf16x8*)(Xb + base) = o0;
    *(bf16x8*)(Xb + base + 8) = o1;
  } else if (blk < 1200) {
    const int wb   = blk - 768;
    const int mat  = wb / 144;
    const int tile = wb - mat * 144;
    const int r0 = (tile / 12) * 64;
    const int c0 = (tile % 12) * 64;
    const float* __restrict__ W = (mat == 0) ? Wq : (mat == 1 ? Wk : Wv);
#pragma unroll
    for (int i = 0; i < 4; ++i) {
      const int r = (t >> 4) + 16 * i;
      const int c = (t & 15) * 4;
      f32x4 v = *(const f32x4*)(W + (size_t)(r0 + r) * HID + c0 + c);
      T[r][c + 0] = f2b(v[0]); T[r][c + 1] = f2b(v[1]);
      T[r][c + 2] = f2b(v[2]); T[r][c + 3] = f2b(v[3]);
    }
    __syncthreads();
    const int cr = t >> 2;
    const int ck = (t & 3) * 16;
    bf16x8 u0, u1;
#pragma unroll
    for (int j = 0; j < 8; ++j) { u0[j] = T[ck + j][cr]; u1[j] = T[ck + 8 + j][cr]; }
    short* orow = Wt + (size_t)(mat * HID + c0 + cr) * HID + r0 + ck;
    *(bf16x8*)orow = u0;
    *(bf16x8*)(orow + 8) = u1;
  } else {
#pragma unroll
    for (int i = 0; i < 4; ++i) {
      const int idx = (t * 4 + i * 1024);
      f32x4 v = *(const f32x4*)(mask + idx);
      v = v * LOG2E - FMAX2;
      *(f32x4*)(mask2 + idx) = v;
    }
  }
}

// ---------------------------------------------------------------------------
// Fused QKV GEMM v2 (byte-identical to round 21): 128x96 tiles, grid 768.
// ---------------------------------------------------------------------------
__global__ __launch_bounds__(256, 3) void qkv_gemm(
    const short* __restrict__ Xb, const short* __restrict__ Wt,
    const float* __restrict__ bq, const float* __restrict__ bk,
    const float* __restrict__ bv,
    short* __restrict__ Qb, short* __restrict__ Kb, short* __restrict__ Vt)
{
  __shared__ __align__(16) short SM[128 * 64 + 96 * 64];
  short (*A_lds)[64] = (short(*)[64])SM;
  short (*B_lds)[64] = (short(*)[64])(SM + 128 * 64);
  short (*Tv)[132]   = (short(*)[132])SM;

  const int tid = threadIdx.x;
  const int w  = tid >> 6;
  const int l  = tid & 63;
  const int lr = l & 15;
  const int g  = l >> 4;
  const int wm = w >> 1;
  const int wn = w & 1;

  const int raw = blockIdx.x;
  const int swz = (raw & 7) * 96 + (raw >> 3);
  const int by  = swz / 24;
  const int bx  = swz - by * 24;
  const int mb0 = by * 128;
  const int nb0 = bx * 96;

  const int lrow8 = l >> 3;
  const int lslot = (l & 7) ^ lrow8;
  const short* __restrict__ pA = Xb + (size_t)(mb0 + w * 32 + lrow8) * HID + lslot * 8;
  const short* __restrict__ pB = Wt + (size_t)(nb0 + w * 24 + lrow8) * HID + lslot * 8;

  f32x4 acc[4][3];
#pragma unroll
  for (int mi = 0; mi < 4; ++mi)
#pragma unroll
    for (int ni = 0; ni < 3; ++ni) acc[mi][ni] = (f32x4){0.f, 0.f, 0.f, 0.f};

  const int rsw = (lr & 7) << 3;

  for (int ks = 0; ks < HID / 64; ++ks) {
    const int k0 = ks * 64;
    __syncthreads();
#pragma unroll
    for (int i = 0; i < 4; ++i)
      __builtin_amdgcn_global_load_lds(
          (const void*)(pA + k0 + i * 8 * HID), (void*)&A_lds[w * 32 + i * 8][0], 16, 0, 0);
#pragma unroll
    for (int i = 0; i < 3; ++i)
      __builtin_amdgcn_global_load_lds(
          (const void*)(pB + k0 + i * 8 * HID), (void*)&B_lds[w * 24 + i * 8][0], 16, 0, 0);
    __syncthreads();

#pragma unroll
    for (int h = 0; h < 2; ++h) {
      const int coff = (((h << 2) | g) << 3) ^ rsw;
      bf16x8 a[4], b[3];
#pragma unroll
      for (int i = 0; i < 4; ++i)
        a[i] = *(const bf16x8*)&A_lds[wm * 64 + 16 * i + lr][coff];
#pragma unroll
      for (int i = 0; i < 3; ++i)
        b[i] = *(const bf16x8*)&B_lds[wn * 48 + 16 * i + lr][coff];
#pragma unroll
      for (int mi = 0; mi < 4; ++mi)
#pragma unroll
        for (int ni = 0; ni < 3; ++ni)
          acc[mi][ni] = __builtin_amdgcn_mfma_f32_16x16x32_bf16(a[mi], b[ni], acc[mi][ni], 0, 0, 0);
    }
  }

  const int mat  = bx >> 3;
  const int n0   = nb0 + wn * 48;
  const int m0   = mb0 + wm * 64;
  const int colb = n0 - mat * HID;

  if (mat < 2) {
    const float* __restrict__ bias = (mat == 0) ? bq : bk;
    short* __restrict__ Out        = (mat == 0) ? Qb : Kb;
#pragma unroll
    for (int ni = 0; ni < 3; ++ni) {
      const int col = colb + 16 * ni + lr;
      const int h = col >> 6, d = col & 63;
      const float bias_v = bias[col];
#pragma unroll
      for (int mi = 0; mi < 4; ++mi) {
        const int mbase = m0 + 16 * mi + 4 * g;
#pragma unroll
        for (int r = 0; r < 4; ++r) {
          const int m = mbase + r;
          const int bb = m >> 11;
          const int s  = m & (SEQ - 1);
          Out[((size_t)(bb * NHEAD + h) * SEQ + s) * HD + d] = f2b(acc[mi][ni][r] + bias_v);
        }
      }
    }
  } else {
    __syncthreads();
#pragma unroll
    for (int ni = 0; ni < 3; ++ni) {
      const int col = colb + 16 * ni + lr;
      const float bias_v = bv[col];
      const int rowl = wn * 48 + 16 * ni + lr;
#pragma unroll
      for (int mi = 0; mi < 4; ++mi) {
        bf16x4 pk;
#pragma unroll
        for (int r = 0; r < 4; ++r) pk[r] = f2b(acc[mi][ni][r] + bias_v);
        *(bf16x4*)&Tv[rowl][wm * 64 + 16 * mi + 4 * g] = pk;
      }
    }
    __syncthreads();
    if (tid < 192) {
      const int row  = tid >> 1;
      const int half = tid & 1;
      const int col  = nb0 - 2 * HID + row;
      const int h = col >> 6, d = col & 63;
      const int bb = mb0 >> 11;
      const int s0 = (mb0 & (SEQ - 1)) + half * 64;
      short* op = Vt + ((size_t)(bb * NHEAD + h) * HD + d) * SEQ + s0;
#pragma unroll
      for (int j = 0; j < 8; ++j)
        *(bf16x8*)(op + 8 * j) = *(const bf16x8*)&Tv[row][half * 64 + 8 * j];
    }
  }
}

// ---------------------------------------------------------------------------
// Flash attention v13: round-21 compute + V-fragment HOIST — all 8 va
// ds_reads issued at tile top (right after prefetch issue), before QK^T,
// so the post-permlane PV start is not gated by ~120-cy LDS reads.
// +32 VGPR (84 -> ~116), under the 128 cap for launch_bounds(256,3).
// ---------------------------------------------------------------------------
__global__ __launch_bounds__(256, 3) void attn_fwd(
    const short* __restrict__ Qb, const short* __restrict__ Kb,
    const short* __restrict__ Vt, const float* __restrict__ mask2,
    float* __restrict__ out)
{
  __shared__ __align__(16) short KA[2][64][64];      // swizzled slots
  __shared__ __align__(16) short VA[2][64][64];      // swizzled slots
  __shared__ float ML[64];                           // merge l exchange

  const int tid  = threadIdx.x;
  const int w    = tid >> 6;         // wave 0..3
  const int pair = w >> 1;           // kv half
  const int pw   = w & 1;            // q half
  const int l    = tid & 63;
  const int r5   = l & 31;
  const int hi   = l >> 5;

  // XCD-locality remap: 768 blocks = 8 XCDs x (3 bh x 32 qblk)
  const int bid  = blockIdx.x;
  const int xcd  = bid & 7;
  const int slot = bid >> 3;
  const int bh   = xcd * 3 + (slot >> 5);
  const int qblk = slot & 31;

  const int b    = bh / 12;
  const int hh   = bh - b * 12;
  const int q0   = qblk * 64 + pw * 32;
  const int kb   = pair * 1024;

  const short* __restrict__ Qh  = Qb + (size_t)bh * SEQ * HD;
  const short* __restrict__ Kh  = Kb + (size_t)bh * SEQ * HD;
  const short* __restrict__ Vth = Vt + (size_t)bh * HD * SEQ;
  const float* __restrict__ mb2 = mask2 + (size_t)b * SEQ;

  bf16x8 qf[4];
#pragma unroll
  for (int j = 0; j < 4; ++j)
    qf[j] = *(const bf16x8*)(Qh + (size_t)(q0 + r5) * HD + 16 * j + 8 * hi);

  f32x16 o0 = (f32x16){0.f};
  f32x16 o1 = (f32x16){0.f};
  float lsum = 0.f;

  // staging geometry (round-21): contiguous loads, swizzled ds_write
  const int lr8 = l >> 3;            // 0..7 row within group
  const int ls8 = l & 7;             // straight slot (source)
  const int ssw2 = ls8 ^ lr8;        // ds_write slot
  const short* __restrict__ Kp = Kh + (size_t)(kb + pw * 32 + lr8) * HD + ls8 * 8;
  const short* __restrict__ Vp = Vth + (size_t)(pw * 32 + lr8) * SEQ + kb + ls8 * 8;
  const int rbase = pw * 32 + lr8;

  bf16x8 kst[4], vst[4];
#pragma unroll
  for (int j = 0; j < 4; ++j) {
    kst[j] = *(const bf16x8*)(Kp + (size_t)(8 * j) * HD);
    vst[j] = *(const bf16x8*)(Vp + (size_t)(8 * j) * SEQ);
  }
#pragma unroll
  for (int j = 0; j < 4; ++j) {
    *(bf16x8*)&KA[pair][rbase + 8 * j][ssw2 * 8] = kst[j];
    *(bf16x8*)&VA[pair][rbase + 8 * j][ssw2 * 8] = vst[j];
  }

  const int rsw = r5 & 7;            // read-row swizzle

  for (int t = 0; t < 16; ++t) {
    const int kv0 = kb + t * 64;
    __syncthreads();   // (1) staged writes of tile t visible

    // issue next tile's global loads (wrap within this pair's half)
    const size_t kvn = (size_t)(((t + 1) & 15) * 64);
#pragma unroll
    for (int j = 0; j < 4; ++j) {
      kst[j] = *(const bf16x8*)(Kp + (size_t)(kvn + 8 * j) * HD);
      vst[j] = *(const bf16x8*)(Vp + (size_t)(8 * j) * SEQ + kvn);
    }

    // HOIST: all PV A-fragments read NOW (data ready; LDS pipe idle here)
    bf16x8 va0[4], va1[4];
#pragma unroll
    for (int j = 0; j < 4; ++j) {
      const int co = ((2 * j + hi) ^ rsw) * 8;
      va0[j] = *(const bf16x8*)&VA[pair][r5][co];
      va1[j] = *(const bf16x8*)&VA[pair][32 + r5][co];
    }

    // S^T = K * Q^T
    f32x16 st0 = (f32x16){0.f};
    f32x16 st1 = (f32x16){0.f};
    __builtin_amdgcn_s_setprio(1);
#pragma unroll
    for (int j = 0; j < 4; ++j) {
      const int co = ((2 * j + hi) ^ rsw) * 8;
      bf16x8 ka0 = *(const bf16x8*)&KA[pair][r5][co];
      bf16x8 ka1 = *(const bf16x8*)&KA[pair][32 + r5][co];
      st0 = __builtin_amdgcn_mfma_f32_32x32x16_bf16(ka0, qf[j], st0, 0, 0, 0);
      st1 = __builtin_amdgcn_mfma_f32_32x32x16_bf16(ka1, qf[j], st1, 0, 0, 0);
    }
    __builtin_amdgcn_s_setprio(0);

    // fixed-max softmax
    float p[2][16];
#pragma unroll
    for (int t2 = 0; t2 < 4; ++t2) {
      f32x4 mv0 = *(const f32x4*)&mb2[kv0 + 8 * t2 + 4 * hi];
      f32x4 mv1 = *(const f32x4*)&mb2[kv0 + 32 + 8 * t2 + 4 * hi];
#pragma unroll
      for (int e = 0; e < 4; ++e) {
        p[0][4 * t2 + e] = fexp2(st0[4 * t2 + e] * C1 + mv0[e]);
        p[1][4 * t2 + e] = fexp2(st1[4 * t2 + e] * C1 + mv1[e]);
      }
    }

    // pack P -> bf16 words; in-register B-frag assembly via permlane32_swap
    unsigned int wq[2][4][2];
#pragma unroll
    for (int s2 = 0; s2 < 2; ++s2)
#pragma unroll
      for (int t2 = 0; t2 < 4; ++t2) {
        asm("v_cvt_pk_bf16_f32 %0, %1, %2"
            : "=v"(wq[s2][t2][0]) : "v"(p[s2][4 * t2 + 0]), "v"(p[s2][4 * t2 + 1]));
        asm("v_cvt_pk_bf16_f32 %0, %1, %2"
            : "=v"(wq[s2][t2][1]) : "v"(p[s2][4 * t2 + 2]), "v"(p[s2][4 * t2 + 3]));
      }

    bf16x8 pf[4];
#pragma unroll
    for (int s2 = 0; s2 < 2; ++s2)
#pragma unroll
      for (int jl = 0; jl < 2; ++jl) {
        unsigned int a0 = wq[s2][2 * jl][0], b0 = wq[s2][2 * jl + 1][0];
        unsigned int a1 = wq[s2][2 * jl][1], b1 = wq[s2][2 * jl + 1][1];
        asm("v_permlane32_swap_b32 %0, %1" : "+v"(a0), "+v"(b0));
        asm("v_permlane32_swap_b32 %0, %1" : "+v"(a1), "+v"(b1));
        uint4 fw; fw.x = a0; fw.y = a1; fw.z = b0; fw.w = b1;
        pf[2 * s2 + jl] = __builtin_bit_cast(bf16x8, fw);
      }

    // per-lane sum tree (cross-half shfl deferred)
    float sm[8];
#pragma unroll
    for (int i = 0; i < 8; ++i)
      sm[i] = (p[0][2 * i] + p[0][2 * i + 1]) + (p[1][2 * i] + p[1][2 * i + 1]);
    lsum += ((sm[0] + sm[1]) + (sm[2] + sm[3])) + ((sm[4] + sm[5]) + (sm[6] + sm[7]));

    // O^T += V^T * P^T (A-frags already in registers)
    __builtin_amdgcn_s_setprio(1);
#pragma unroll
    for (int j = 0; j < 4; ++j) {
      o0 = __builtin_amdgcn_mfma_f32_32x32x16_bf16(va0[j], pf[j], o0, 0, 0, 0);
      o1 = __builtin_amdgcn_mfma_f32_32x32x16_bf16(va1[j], pf[j], o1, 0, 0, 0);
    }
    __builtin_amdgcn_s_setprio(0);

    __syncthreads();   // (2) all reads of tile t done -> safe to overwrite
#pragma unroll
    for (int j = 0; j < 4; ++j) {
      *(bf16x8*)&KA[pair][rbase + 8 * j][ssw2 * 8] = kst[j];
      *(bf16x8*)&VA[pair][rbase + 8 * j][ssw2 * 8] = vst[j];
    }
  }

  // deferred cross-half reduce
  const float l_run = lsum + __shfl_xor(lsum, 32, 64);

  // ---- cross-pair merge: waves 2,3 publish (l,O); waves 0,1 combine ----
  __syncthreads();
  float* Os = (float*)&KA[0][0][0];   // [2][32][64] f32 = 16384 B, fits KA

  if (w >= 2) {
    const int wv = w - 2;
    float* Or = Os + (size_t)(wv * 32 + r5) * 64;
#pragma unroll
    for (int t2 = 0; t2 < 4; ++t2) {
      f32x4 v0, v1;
#pragma unroll
      for (int e = 0; e < 4; ++e) { v0[e] = o0[4 * t2 + e]; v1[e] = o1[4 * t2 + e]; }
      *(f32x4*)&Or[8 * t2 + 4 * hi]      = v0;
      *(f32x4*)&Or[32 + 8 * t2 + 4 * hi] = v1;
    }
    if (hi == 0) ML[wv * 32 + r5] = l_run;
  }
  __syncthreads();
  if (w < 2) {
    const float lo  = ML[w * 32 + r5];
    const float inv = 1.f / (l_run + lo);
    const float* Or = Os + (size_t)(w * 32 + r5) * 64;
    float* ob = out + (size_t)(b * SEQ + q0 + r5) * HID + hh * HD;
#pragma unroll
    for (int t2 = 0; t2 < 4; ++t2) {
      f32x4 po = *(const f32x4*)&Or[8 * t2 + 4 * hi];
      f32x4 p1 = *(const f32x4*)&Or[32 + 8 * t2 + 4 * hi];
      f32x4 v0, v1;
#pragma unroll
      for (int e = 0; e < 4; ++e) {
        v0[e] = (o0[4 * t2 + e] + po[e]) * inv;
        v1[e] = (o1[4 * t2 + e] + p1[e]) * inv;
      }
      *(f32x4*)&ob[8 * t2 + 4 * hi]      = v0;
      *(f32x4*)&ob[32 + 8 * t2 + 4 * hi] = v1;
    }
  }
}

// ---------------------------------------------------------------------------
extern "C" void kernel_launch(void* const* d_in, const int* in_sizes, int n_in,
                              void* d_out, int out_size, void* d_ws, size_t ws_size,
                              hipStream_t stream) {
  const float* X    = (const float*)d_in[0];
  const float* mask = (const float*)d_in[1];
  const float* Wq   = (const float*)d_in[2];
  const float* bq   = (const float*)d_in[3];
  const float* Wk   = (const float*)d_in[4];
  const float* bk   = (const float*)d_in[5];
  const float* Wv   = (const float*)d_in[6];
  const float* bv   = (const float*)d_in[7];
  float* out = (float*)d_out;

  short* Qb = (short*)d_ws;
  short* Kb = Qb + PH;
  short* Vt = Kb + PH;                 // V stored transposed [bh][d][s]
  short* Xb = Vt + PH;
  short* Wt = Xb + XEL;
  float* mask2 = (float*)(Wt + (size_t)3 * HID * HID);

  prep<<<dim3(1201), 256, 0, stream>>>(X, Wq, Wk, Wv, mask, Xb, Wt, mask2);
  qkv_gemm<<<dim3(768), 256, 0, stream>>>(Xb, Wt, bq, bk, bv, Qb, Kb, Vt);
  attn_fwd<<<dim3(768), 256, 0, stream>>>(Qb, Kb, Vt, mask2, out);
}

// Round 23
// 73.965 us; speedup vs baseline: 1.3284x; 1.3284x over previous
//
#include <hip/hip_runtime.h>

#define HID 768
#define NHEAD 12
#define HD 64
#define SEQ 2048
#define BATCH 2
#define PH (BATCH * NHEAD * SEQ * HD)   // 3,145,728 elements per Q/K/V plane
#define XEL (BATCH * SEQ * HID)
#define LOG2E 1.4426950408889634f
#define C1 (0.125f * LOG2E)             // QK scale folded with log2e
#define FMAX2 16.0f                     // fixed softmax max (log2 domain)

typedef __attribute__((ext_vector_type(8))) short bf16x8;
typedef __attribute__((ext_vector_type(4))) short bf16x4;
typedef __attribute__((ext_vector_type(4))) float f32x4;
typedef __attribute__((ext_vector_type(16))) float f32x16;

static __device__ __forceinline__ short f2b(float f) {
  unsigned int u = __builtin_bit_cast(unsigned int, f);
  unsigned int r = (u + 0x7fffu + ((u >> 16) & 1u)) >> 16;
  return (short)(unsigned short)r;
}

static __device__ __forceinline__ float fexp2(float x) {
  float r; asm("v_exp_f32 %0, %1" : "=v"(r) : "v"(x)); return r;
}

// ---------------------------------------------------------------------------
// Prep: X->bf16, W transpose->Wt[n][k] bf16, mask2 = mask*log2e - FMAX2
// ---------------------------------------------------------------------------
__global__ __launch_bounds__(256) void prep(
    const float* __restrict__ X,
    const float* __restrict__ Wq, const float* __restrict__ Wk,
    const float* __restrict__ Wv, const float* __restrict__ mask,
    short* __restrict__ Xb, short* __restrict__ Wt, float* __restrict__ mask2)
{
  __shared__ short T[64][65];
  const int t = threadIdx.x;
  const int blk = blockIdx.x;
  if (blk < 768) {
    const size_t base = (size_t)blk * 4096 + t * 16;
    f32x4 a0 = *(const f32x4*)(X + base);
    f32x4 a1 = *(const f32x4*)(X + base + 4);
    f32x4 a2 = *(const f32x4*)(X + base + 8);
    f32x4 a3 = *(const f32x4*)(X + base + 12);
    bf16x8 o0, o1;
#pragma unroll
    for (int i = 0; i < 4; ++i) {
      o0[i] = f2b(a0[i]); o0[4 + i] = f2b(a1[i]);
      o1[i] = f2b(a2[i]); o1[4 + i] = f2b(a3[i]);
    }
    *(bf16x8*)(Xb + base) = o0;
    *(bf16x8*)(Xb + base + 8) = o1;
  } else if (blk < 1200) {
    const int wb   = blk - 768;
    const int mat  = wb / 144;
    const int tile = wb - mat * 144;
    const int r0 = (tile / 12) * 64;
    const int c0 = (tile % 12) * 64;
    const float* __restrict__ W = (mat == 0) ? Wq : (mat == 1 ? Wk : Wv);
#pragma unroll
    for (int i = 0; i < 4; ++i) {
      const int r = (t >> 4) + 16 * i;
      const int c = (t & 15) * 4;
      f32x4 v = *(const f32x4*)(W + (size_t)(r0 + r) * HID + c0 + c);
      T[r][c + 0] = f2b(v[0]); T[r][c + 1] = f2b(v[1]);
      T[r][c + 2] = f2b(v[2]); T[r][c + 3] = f2b(v[3]);
    }
    __syncthreads();
    const int cr = t >> 2;
    const int ck = (t & 3) * 16;
    bf16x8 u0, u1;
#pragma unroll
    for (int j = 0; j < 8; ++j) { u0[j] = T[ck + j][cr]; u1[j] = T[ck + 8 + j][cr]; }
    short* orow = Wt + (size_t)(mat * HID + c0 + cr) * HID + r0 + ck;
    *(bf16x8*)orow = u0;
    *(bf16x8*)(orow + 8) = u1;
  } else {
#pragma unroll
    for (int i = 0; i < 4; ++i) {
      const int idx = (t * 4 + i * 1024);
      f32x4 v = *(const f32x4*)(mask + idx);
      v = v * LOG2E - FMAX2;
      *(f32x4*)(mask2 + idx) = v;
    }
  }
}

// ---------------------------------------------------------------------------
// Fused QKV GEMM v2: 128x96 tiles, grid 768 = 3.0 blocks/CU exact.
// ---------------------------------------------------------------------------
__global__ __launch_bounds__(256, 3) void qkv_gemm(
    const short* __restrict__ Xb, const short* __restrict__ Wt,
    const float* __restrict__ bq, const float* __restrict__ bk,
    const float* __restrict__ bv,
    short* __restrict__ Qb, short* __restrict__ Kb, short* __restrict__ Vt)
{
  __shared__ __align__(16) short SM[128 * 64 + 96 * 64];
  short (*A_lds)[64] = (short(*)[64])SM;
  short (*B_lds)[64] = (short(*)[64])(SM + 128 * 64);
  short (*Tv)[132]   = (short(*)[132])SM;

  const int tid = threadIdx.x;
  const int w  = tid >> 6;
  const int l  = tid & 63;
  const int lr = l & 15;
  const int g  = l >> 4;
  const int wm = w >> 1;
  const int wn = w & 1;

  const int raw = blockIdx.x;
  const int swz = (raw & 7) * 96 + (raw >> 3);
  const int by  = swz / 24;
  const int bx  = swz - by * 24;
  const int mb0 = by * 128;
  const int nb0 = bx * 96;

  const int lrow8 = l >> 3;
  const int lslot = (l & 7) ^ lrow8;
  const short* __restrict__ pA = Xb + (size_t)(mb0 + w * 32 + lrow8) * HID + lslot * 8;
  const short* __restrict__ pB = Wt + (size_t)(nb0 + w * 24 + lrow8) * HID + lslot * 8;

  f32x4 acc[4][3];
#pragma unroll
  for (int mi = 0; mi < 4; ++mi)
#pragma unroll
    for (int ni = 0; ni < 3; ++ni) acc[mi][ni] = (f32x4){0.f, 0.f, 0.f, 0.f};

  const int rsw = (lr & 7) << 3;

  for (int ks = 0; ks < HID / 64; ++ks) {
    const int k0 = ks * 64;
    __syncthreads();
#pragma unroll
    for (int i = 0; i < 4; ++i)
      __builtin_amdgcn_global_load_lds(
          (const void*)(pA + k0 + i * 8 * HID), (void*)&A_lds[w * 32 + i * 8][0], 16, 0, 0);
#pragma unroll
    for (int i = 0; i < 3; ++i)
      __builtin_amdgcn_global_load_lds(
          (const void*)(pB + k0 + i * 8 * HID), (void*)&B_lds[w * 24 + i * 8][0], 16, 0, 0);
    __syncthreads();

#pragma unroll
    for (int h = 0; h < 2; ++h) {
      const int coff = (((h << 2) | g) << 3) ^ rsw;
      bf16x8 a[4], b[3];
#pragma unroll
      for (int i = 0; i < 4; ++i)
        a[i] = *(const bf16x8*)&A_lds[wm * 64 + 16 * i + lr][coff];
#pragma unroll
      for (int i = 0; i < 3; ++i)
        b[i] = *(const bf16x8*)&B_lds[wn * 48 + 16 * i + lr][coff];
#pragma unroll
      for (int mi = 0; mi < 4; ++mi)
#pragma unroll
        for (int ni = 0; ni < 3; ++ni)
          acc[mi][ni] = __builtin_amdgcn_mfma_f32_16x16x32_bf16(a[mi], b[ni], acc[mi][ni], 0, 0, 0);
    }
  }

  const int mat  = bx >> 3;
  const int n0   = nb0 + wn * 48;
  const int m0   = mb0 + wm * 64;
  const int colb = n0 - mat * HID;

  if (mat < 2) {
    const float* __restrict__ bias = (mat == 0) ? bq : bk;
    short* __restrict__ Out        = (mat == 0) ? Qb : Kb;
#pragma unroll
    for (int ni = 0; ni < 3; ++ni) {
      const int col = colb + 16 * ni + lr;
      const int h = col >> 6, d = col & 63;
      const float bias_v = bias[col];
#pragma unroll
      for (int mi = 0; mi < 4; ++mi) {
        const int mbase = m0 + 16 * mi + 4 * g;
#pragma unroll
        for (int r = 0; r < 4; ++r) {
          const int m = mbase + r;
          const int bb = m >> 11;
          const int s  = m & (SEQ - 1);
          Out[((size_t)(bb * NHEAD + h) * SEQ + s) * HD + d] = f2b(acc[mi][ni][r] + bias_v);
        }
      }
    }
  } else {
    __syncthreads();
#pragma unroll
    for (int ni = 0; ni < 3; ++ni) {
      const int col = colb + 16 * ni + lr;
      const float bias_v = bv[col];
      const int rowl = wn * 48 + 16 * ni + lr;
#pragma unroll
      for (int mi = 0; mi < 4; ++mi) {
        bf16x4 pk;
#pragma unroll
        for (int r = 0; r < 4; ++r) pk[r] = f2b(acc[mi][ni][r] + bias_v);
        *(bf16x4*)&Tv[rowl][wm * 64 + 16 * mi + 4 * g] = pk;
      }
    }
    __syncthreads();
    if (tid < 192) {
      const int row  = tid >> 1;
      const int half = tid & 1;
      const int col  = nb0 - 2 * HID + row;
      const int h = col >> 6, d = col & 63;
      const int bb = mb0 >> 11;
      const int s0 = (mb0 & (SEQ - 1)) + half * 64;
      short* op = Vt + ((size_t)(bb * NHEAD + h) * HD + d) * SEQ + s0;
#pragma unroll
      for (int j = 0; j < 8; ++j)
        *(bf16x8*)(op + 8 * j) = *(const bf16x8*)&Tv[row][half * 64 + 8 * j];
    }
  }
}

// ---------------------------------------------------------------------------
// Flash attention v12 (round-21 verified best): contiguous staging loads,
// swizzled ds_write; fixed-max exp2 softmax; permlane32_swap in-register P;
// deferred l-reduce; kv-split merge. NO va-hoist (round-22 spill lesson).
// ---------------------------------------------------------------------------
__global__ __launch_bounds__(256, 3) void attn_fwd(
    const short* __restrict__ Qb, const short* __restrict__ Kb,
    const short* __restrict__ Vt, const float* __restrict__ mask2,
    float* __restrict__ out)
{
  __shared__ __align__(16) short KA[2][64][64];      // swizzled slots
  __shared__ __align__(16) short VA[2][64][64];      // swizzled slots
  __shared__ float ML[64];                           // merge l exchange

  const int tid  = threadIdx.x;
  const int w    = tid >> 6;         // wave 0..3
  const int pair = w >> 1;           // kv half
  const int pw   = w & 1;            // q half
  const int l    = tid & 63;
  const int r5   = l & 31;
  const int hi   = l >> 5;

  // XCD-locality remap: 768 blocks = 8 XCDs x (3 bh x 32 qblk)
  const int bid  = blockIdx.x;
  const int xcd  = bid & 7;
  const int slot = bid >> 3;
  const int bh   = xcd * 3 + (slot >> 5);
  const int qblk = slot & 31;

  const int b    = bh / 12;
  const int hh   = bh - b * 12;
  const int q0   = qblk * 64 + pw * 32;
  const int kb   = pair * 1024;

  const short* __restrict__ Qh  = Qb + (size_t)bh * SEQ * HD;
  const short* __restrict__ Kh  = Kb + (size_t)bh * SEQ * HD;
  const short* __restrict__ Vth = Vt + (size_t)bh * HD * SEQ;
  const float* __restrict__ mb2 = mask2 + (size_t)b * SEQ;

  bf16x8 qf[4];
#pragma unroll
  for (int j = 0; j < 4; ++j)
    qf[j] = *(const bf16x8*)(Qh + (size_t)(q0 + r5) * HD + 16 * j + 8 * hi);

  f32x16 o0 = (f32x16){0.f};
  f32x16 o1 = (f32x16){0.f};
  float lsum = 0.f;

  // staging geometry: contiguous loads, swizzled ds_write
  const int lr8 = l >> 3;            // 0..7 row within group
  const int ls8 = l & 7;             // straight slot (source)
  const int ssw2 = ls8 ^ lr8;        // ds_write slot
  const short* __restrict__ Kp = Kh + (size_t)(kb + pw * 32 + lr8) * HD + ls8 * 8;
  const short* __restrict__ Vp = Vth + (size_t)(pw * 32 + lr8) * SEQ + kb + ls8 * 8;
  const int rbase = pw * 32 + lr8;

  bf16x8 kst[4], vst[4];
#pragma unroll
  for (int j = 0; j < 4; ++j) {
    kst[j] = *(const bf16x8*)(Kp + (size_t)(8 * j) * HD);
    vst[j] = *(const bf16x8*)(Vp + (size_t)(8 * j) * SEQ);
  }
#pragma unroll
  for (int j = 0; j < 4; ++j) {
    *(bf16x8*)&KA[pair][rbase + 8 * j][ssw2 * 8] = kst[j];
    *(bf16x8*)&VA[pair][rbase + 8 * j][ssw2 * 8] = vst[j];
  }

  const int rsw = r5 & 7;            // read-row swizzle

  for (int t = 0; t < 16; ++t) {
    const int kv0 = kb + t * 64;
    __syncthreads();   // (1) staged writes of tile t visible

    // issue next tile's global loads (wrap within this pair's half)
    const size_t kvn = (size_t)(((t + 1) & 15) * 64);
#pragma unroll
    for (int j = 0; j < 4; ++j) {
      kst[j] = *(const bf16x8*)(Kp + (size_t)(kvn + 8 * j) * HD);
      vst[j] = *(const bf16x8*)(Vp + (size_t)(8 * j) * SEQ + kvn);
    }

    // S^T = K * Q^T
    f32x16 st0 = (f32x16){0.f};
    f32x16 st1 = (f32x16){0.f};
    __builtin_amdgcn_s_setprio(1);
#pragma unroll
    for (int j = 0; j < 4; ++j) {
      const int co = ((2 * j + hi) ^ rsw) * 8;
      bf16x8 ka0 = *(const bf16x8*)&KA[pair][r5][co];
      bf16x8 ka1 = *(const bf16x8*)&KA[pair][32 + r5][co];
      st0 = __builtin_amdgcn_mfma_f32_32x32x16_bf16(ka0, qf[j], st0, 0, 0, 0);
      st1 = __builtin_amdgcn_mfma_f32_32x32x16_bf16(ka1, qf[j], st1, 0, 0, 0);
    }
    __builtin_amdgcn_s_setprio(0);

    // fixed-max softmax
    float p[2][16];
#pragma unroll
    for (int t2 = 0; t2 < 4; ++t2) {
      f32x4 mv0 = *(const f32x4*)&mb2[kv0 + 8 * t2 + 4 * hi];
      f32x4 mv1 = *(const f32x4*)&mb2[kv0 + 32 + 8 * t2 + 4 * hi];
#pragma unroll
      for (int e = 0; e < 4; ++e) {
        p[0][4 * t2 + e] = fexp2(st0[4 * t2 + e] * C1 + mv0[e]);
        p[1][4 * t2 + e] = fexp2(st1[4 * t2 + e] * C1 + mv1[e]);
      }
    }

    // pack P -> bf16 words; in-register B-frag assembly via permlane32_swap
    unsigned int wq[2][4][2];
#pragma unroll
    for (int s2 = 0; s2 < 2; ++s2)
#pragma unroll
      for (int t2 = 0; t2 < 4; ++t2) {
        asm("v_cvt_pk_bf16_f32 %0, %1, %2"
            : "=v"(wq[s2][t2][0]) : "v"(p[s2][4 * t2 + 0]), "v"(p[s2][4 * t2 + 1]));
        asm("v_cvt_pk_bf16_f32 %0, %1, %2"
            : "=v"(wq[s2][t2][1]) : "v"(p[s2][4 * t2 + 2]), "v"(p[s2][4 * t2 + 3]));
      }

    bf16x8 pf[4];
#pragma unroll
    for (int s2 = 0; s2 < 2; ++s2)
#pragma unroll
      for (int jl = 0; jl < 2; ++jl) {
        unsigned int a0 = wq[s2][2 * jl][0], b0 = wq[s2][2 * jl + 1][0];
        unsigned int a1 = wq[s2][2 * jl][1], b1 = wq[s2][2 * jl + 1][1];
        asm("v_permlane32_swap_b32 %0, %1" : "+v"(a0), "+v"(b0));
        asm("v_permlane32_swap_b32 %0, %1" : "+v"(a1), "+v"(b1));
        uint4 fw; fw.x = a0; fw.y = a1; fw.z = b0; fw.w = b1;
        pf[2 * s2 + jl] = __builtin_bit_cast(bf16x8, fw);
      }

    // per-lane sum tree (cross-half shfl deferred)
    float sm[8];
#pragma unroll
    for (int i = 0; i < 8; ++i)
      sm[i] = (p[0][2 * i] + p[0][2 * i + 1]) + (p[1][2 * i] + p[1][2 * i + 1]);
    lsum += ((sm[0] + sm[1]) + (sm[2] + sm[3])) + ((sm[4] + sm[5]) + (sm[6] + sm[7]));

    // O^T += V^T * P^T
    __builtin_amdgcn_s_setprio(1);
#pragma unroll
    for (int j = 0; j < 4; ++j) {
      const int co = ((2 * j + hi) ^ rsw) * 8;
      bf16x8 va0 = *(const bf16x8*)&VA[pair][r5][co];
      bf16x8 va1 = *(const bf16x8*)&VA[pair][32 + r5][co];
      o0 = __builtin_amdgcn_mfma_f32_32x32x16_bf16(va0, pf[j], o0, 0, 0, 0);
      o1 = __builtin_amdgcn_mfma_f32_32x32x16_bf16(va1, pf[j], o1, 0, 0, 0);
    }
    __builtin_amdgcn_s_setprio(0);

    __syncthreads();   // (2) all reads of tile t done -> safe to overwrite
#pragma unroll
    for (int j = 0; j < 4; ++j) {
      *(bf16x8*)&KA[pair][rbase + 8 * j][ssw2 * 8] = kst[j];
      *(bf16x8*)&VA[pair][rbase + 8 * j][ssw2 * 8] = vst[j];
    }
  }

  // deferred cross-half reduce
  const float l_run = lsum + __shfl_xor(lsum, 32, 64);

  // ---- cross-pair merge: waves 2,3 publish (l,O); waves 0,1 combine ----
  __syncthreads();
  float* Os = (float*)&KA[0][0][0];   // [2][32][64] f32 = 16384 B, fits KA

  if (w >= 2) {
    const int wv = w - 2;
    float* Or = Os + (size_t)(wv * 32 + r5) * 64;
#pragma unroll
    for (int t2 = 0; t2 < 4; ++t2) {
      f32x4 v0, v1;
#pragma unroll
      for (int e = 0; e < 4; ++e) { v0[e] = o0[4 * t2 + e]; v1[e] = o1[4 * t2 + e]; }
      *(f32x4*)&Or[8 * t2 + 4 * hi]      = v0;
      *(f32x4*)&Or[32 + 8 * t2 + 4 * hi] = v1;
    }
    if (hi == 0) ML[wv * 32 + r5] = l_run;
  }
  __syncthreads();
  if (w < 2) {
    const float lo  = ML[w * 32 + r5];
    const float inv = 1.f / (l_run + lo);
    const float* Or = Os + (size_t)(w * 32 + r5) * 64;
    float* ob = out + (size_t)(b * SEQ + q0 + r5) * HID + hh * HD;
#pragma unroll
    for (int t2 = 0; t2 < 4; ++t2) {
      f32x4 po = *(const f32x4*)&Or[8 * t2 + 4 * hi];
      f32x4 p1 = *(const f32x4*)&Or[32 + 8 * t2 + 4 * hi];
      f32x4 v0, v1;
#pragma unroll
      for (int e = 0; e < 4; ++e) {
        v0[e] = (o0[4 * t2 + e] + po[e]) * inv;
        v1[e] = (o1[4 * t2 + e] + p1[e]) * inv;
      }
      *(f32x4*)&ob[8 * t2 + 4 * hi]      = v0;
      *(f32x4*)&ob[32 + 8 * t2 + 4 * hi] = v1;
    }
  }
}

// ---------------------------------------------------------------------------
extern "C" void kernel_launch(void* const* d_in, const int* in_sizes, int n_in,
                              void* d_out, int out_size, void* d_ws, size_t ws_size,
                              hipStream_t stream) {
  const float* X    = (const float*)d_in[0];
  const float* mask = (const float*)d_in[1];
  const float* Wq   = (const float*)d_in[2];
  const float* bq   = (const float*)d_in[3];
  const float* Wk   = (const float*)d_in[4];
  const float* bk   = (const float*)d_in[5];
  const float* Wv   = (const float*)d_in[6];
  const float* bv   = (const float*)d_in[7];
  float* out = (float*)d_out;

  short* Qb = (short*)d_ws;
  short* Kb = Qb + PH;
  short* Vt = Kb + PH;                 // V stored transposed [bh][d][s]
  short* Xb = Vt + PH;
  short* Wt = Xb + XEL;
  float* mask2 = (float*)(Wt + (size_t)3 * HID * HID);

  prep<<<dim3(1201), 256, 0, stream>>>(X, Wq, Wk, Wv, mask, Xb, Wt, mask2);
  qkv_gemm<<<dim3(768), 256, 0, stream>>>(Xb, Wt, bq, bk, bv, Qb, Kb, Vt);
  attn_fwd<<<dim3(768), 256, 0, stream>>>(Qb, Kb, Vt, mask2, out);
}